// Round 10
// baseline (657.921 us; speedup 1.0000x reference)
//
#include <hip/hip_runtime.h>

// MyRNN: B=128, T=80, E=100, V=10000, U=512
// 8 clusters x 32 member-blocks formed dynamically by physical XCD
// (s_getreg HW_REG_XCC_ID + atomic slot grab); 1 block/CU, grid 256 -> each
// XCD hosts exactly 32 blocks; cluster c owns batch rows [16c,16c+16);
// member m owns cols [16m,16m+16) of rk0/rk1/k1 (LDS, hi/lo bf16 split).
// Protocol history: R7 745 -> R9 588 (parallel MALL flags) -> R12 572 (BEST:
// sE overlap, w0-poll, 128B flag lines). R8/R10/R11/R15/R16 bracket the
// exchange latency L ~ 2.3-2.65us as MALL propagation physics: six distinct
// signaling mechanisms all land there (R16 atomic posts: exactly neutral).
// R13 (652): row-split duplicated MFMA. R14 (826): direct-to-register
// consumption CORRECT but 16 serialized polls killed it. Lesson fusion ->
// R17: R12's one-shot wave-parallel poll + R14's register-direct fragment
// consumption, ZERO barriers after the prologue:
//   - each wave autonomous: poll all 32 flags in one shot, bulk-issue 32
//     dwordx4 sc0 fragment loads, unpack hi/lo in regs, MFMA. No sH/sE/sK0
//     LDS (k0 frags + emb rows loaded per-lane directly).
//   - hPk double-buffered by t-parity. WAR audit: h0 overwrite at t+1 is
//     after poll h-flags(2t+2), posted by wave1s after consuming h0(t) [OK];
//     h-parity-p overwrite at t+2 is after wave1's poll h-flags(2t+4),
//     posted by every member's wave1 after its t+1 reads of parity-p [OK];
//     wave0's t+1 reads of parity-(t&1) precede its post(2t+3), which gates
//     wave1's t+1 h-writes to the OTHER parity [OK].
//   - single monotone flag/member: w0 writes 2t+1, w1 writes 2t+2; w1's
//     write is ordered after observing >=2t+1 on its own member via its
//     poll, so the word only ascends. Deadlock-free (posts unconditional).

typedef __attribute__((ext_vector_type(8))) short short8;
typedef __attribute__((ext_vector_type(4))) float f32x4;
typedef __attribute__((ext_vector_type(4))) unsigned uint4v;

#define MFMA16(a,b,c) __builtin_amdgcn_mfma_f32_16x16x32_bf16(a,b,c,0,0,0)
#define LOAD_RLX(p)    __hip_atomic_load((p), __ATOMIC_RELAXED, __HIP_MEMORY_SCOPE_AGENT)
#define STORE_RLX(p,v) __hip_atomic_store((p), (v), __ATOMIC_RELAXED, __HIP_MEMORY_SCOPE_AGENT)
#define ADD_RLX(p,v)   __hip_atomic_fetch_add((p), (v), __ATOMIC_RELAXED, __HIP_MEMORY_SCOPE_AGENT)
#define GLOAD4(dst, addr) asm volatile("global_load_dwordx4 %0, %1, off sc0" : "=v"(dst) : "v"(addr))

__device__ __forceinline__ short f2bf(float v){
  unsigned u = __float_as_uint(v);
  u = (u + 0x7fffu + ((u >> 16) & 1u)) >> 16;   // RNE to bf16
  return (short)u;
}
__device__ __forceinline__ float bf2f(short s){
  return __uint_as_float(((unsigned)(unsigned short)s) << 16);
}
__device__ __forceinline__ float fast_tanh(float x){
  x = fminf(15.f, fmaxf(-15.f, x));
  float e = __expf(2.f * x);
  return (e - 1.f) * __builtin_amdgcn_rcpf(e + 1.f);
}

__launch_bounds__(128, 1)
__global__ void rnn_kernel(const int* __restrict__ tokens,
                           const float* __restrict__ emb,
                           const float* __restrict__ k0,
                           const float* __restrict__ rk0,
                           const float* __restrict__ b0,
                           const float* __restrict__ k1,
                           const float* __restrict__ rk1,
                           const float* __restrict__ b1,
                           const float* __restrict__ wd,
                           const float* __restrict__ bd,
                           float* __restrict__ out,
                           char* __restrict__ ws)
{
  constexpr int T = 80, E = 100, U = 512;
  const int tid  = threadIdx.x;
  const int w    = tid >> 6;          // wave id (0/1)
  const int lane = tid & 63;
  const int m    = lane & 15;         // A-row / B,C col
  const int q    = lane >> 4;         // quad 0..3

  __shared__ __align__(16) short sW[6][16][520];   // rk0 hi/lo, rk1 hi/lo, k1 hi/lo : [col][k]
  __shared__ int   sTok[16][80];
  __shared__ float sB0[16], sB1[16];
  __shared__ int   sReg[2];

  int*      regCnt = (int*)(ws + 512);             // 8 registration counters (MALL)
  int*      flags  = (int*)(ws + 4096);            // 256 member flags, 128B stride (MALL)
  unsigned* h0Pk   = (unsigned*)(ws + 40960);      // h0 packed (hi<<16|lo), [128][512]
  unsigned* hPkA   = h0Pk + 128*U;                 // h packed, parity 0
  unsigned* hPkB   = hPkA + 128*U;                 // h packed, parity 1

  // -------- dynamic cluster formation: cluster id = physical XCD --------
  int xcc;
  asm volatile("s_getreg_b32 %0, hwreg(HW_REG_XCC_ID)" : "=s"(xcc));
  if (tid == 0){
    int slot = ADD_RLX(regCnt + (xcc & 7)*16, 1);  // 0..31 within this XCD
    sReg[0] = xcc & 7;
    sReg[1] = slot;
  }
  __syncthreads();
  const int cl  = sReg[0];
  const int mem = sReg[1];
  int* const myFlag   = flags + (cl*32 + mem)*32;         // 128B stride
  int* const pollAddr = flags + (cl*32 + (lane & 31))*32; // lane -> member flag

  // ---------------- prologue: stationary weights -> LDS ----------------
  const float* mats[3] = { rk0, rk1, k1 };
  for (int mi = 0; mi < 3; ++mi){
    const float* G = mats[mi];
    for (int i = tid; i < 16*U; i += 128){
      int k = i >> 4, c = i & 15;
      float v  = G[k*U + mem*16 + c];
      short hi = f2bf(v);
      short lo = f2bf(v - bf2f(hi));
      sW[2*mi+0][c][k] = hi;
      sW[2*mi+1][c][k] = lo;
    }
  }
  for (int i = tid; i < 16*T; i += 128){
    int r = i / T, t = i - r*T;
    sTok[r][t] = tokens[(cl*16 + r)*T + t];
  }
  if (tid < 16){ sB0[tid] = b0[mem*16 + tid]; sB1[tid] = b1[mem*16 + tid]; }
  __syncthreads();
  // -------- after this point: NO __syncthreads. Waves are autonomous. ----

  // per-lane constant k0 B-fragments (col m, k = kk*32+q*8+j), zero-padded
  short8 k0h[4], k0l[4];
  #pragma unroll
  for (int kk = 0; kk < 4; ++kk){
    #pragma unroll
    for (int j = 0; j < 8; ++j){
      int k = kk*32 + q*8 + j;
      float v = (k < E) ? k0[k*U + mem*16 + m] : 0.f;
      short hi = f2bf(v);
      short lo = f2bf(v - bf2f(hi));
      k0h[kk][j] = hi; k0l[kk][j] = lo;
    }
  }

  // one-shot wave-parallel poll (R12 primitive; called independently per wave)
  auto pollF = [&](int target){
    while (__any(LOAD_RLX(pollAddr) < target)) {}
  };
  // post: drain data stores (vmcnt ack), then lane0 agent-stores round id
  auto postF = [&](int val){
    asm volatile("s_waitcnt vmcnt(0)" ::: "memory");
    if (lane == 0) STORE_RLX(myFlag, val);
  };
  // bulk register-direct consumption (R14-verified layout): issue 32 dwordx4
  // sc0 covering this lane's A-fragments (row m, k = kk*32+q*8+0..7), then
  // two waitcnt-staged halves of unpack+MFMA with sW[wsH]/sW[wsL].
  auto mm16 = [&](const unsigned* src, int wsH, int wsL,
                  f32x4& Za, f32x4& Zb, f32x4& Zc, f32x4& Zd){
    const unsigned* pa = src + (cl*16 + m)*U + q*8;
    uint4 r[32];
    #pragma unroll
    for (int kk = 0; kk < 16; ++kk){
      GLOAD4(r[2*kk],   pa + 32*kk);
      GLOAD4(r[2*kk+1], pa + 32*kk + 4);
    }
    asm volatile("s_waitcnt vmcnt(16)" ::: "memory");   // kk 0..7 landed
    __builtin_amdgcn_sched_barrier(0);                  // rule 18
    #pragma unroll
    for (int kk = 0; kk < 8; ++kk){
      uint4 c0 = r[2*kk], c1 = r[2*kk+1];
      uint4v hh, ll;
      hh.x = (c0.x >> 16)     | (c0.y & 0xffff0000u);
      hh.y = (c0.z >> 16)     | (c0.w & 0xffff0000u);
      hh.z = (c1.x >> 16)     | (c1.y & 0xffff0000u);
      hh.w = (c1.z >> 16)     | (c1.w & 0xffff0000u);
      ll.x = (c0.x & 0xffffu) | (c0.y << 16);
      ll.y = (c0.z & 0xffffu) | (c0.w << 16);
      ll.z = (c1.x & 0xffffu) | (c1.y << 16);
      ll.w = (c1.z & 0xffffu) | (c1.w << 16);
      short8 ah = __builtin_bit_cast(short8, hh);
      short8 al = __builtin_bit_cast(short8, ll);
      short8 bh = *(const short8*)&sW[wsH][m][kk*32 + q*8];
      short8 bl = *(const short8*)&sW[wsL][m][kk*32 + q*8];
      Za = MFMA16(ah, bh, Za); Zb = MFMA16(al, bh, Zb);
      Zc = MFMA16(ah, bl, Zc); Zd = MFMA16(al, bl, Zd);
    }
    asm volatile("s_waitcnt vmcnt(0)" ::: "memory");    // kk 8..15 landed
    __builtin_amdgcn_sched_barrier(0);
    #pragma unroll
    for (int kk = 8; kk < 16; ++kk){
      uint4 c0 = r[2*kk], c1 = r[2*kk+1];
      uint4v hh, ll;
      hh.x = (c0.x >> 16)     | (c0.y & 0xffff0000u);
      hh.y = (c0.z >> 16)     | (c0.w & 0xffff0000u);
      hh.z = (c1.x >> 16)     | (c1.y & 0xffff0000u);
      hh.w = (c1.z >> 16)     | (c1.w & 0xffff0000u);
      ll.x = (c0.x & 0xffffu) | (c0.y << 16);
      ll.y = (c0.z & 0xffffu) | (c0.w << 16);
      ll.z = (c1.x & 0xffffu) | (c1.y << 16);
      ll.w = (c1.z & 0xffffu) | (c1.w << 16);
      short8 ah = __builtin_bit_cast(short8, hh);
      short8 al = __builtin_bit_cast(short8, ll);
      short8 bh = *(const short8*)&sW[wsH][m][kk*32 + q*8];
      short8 bl = *(const short8*)&sW[wsL][m][kk*32 + q*8];
      Za = MFMA16(ah, bh, Za); Zb = MFMA16(al, bh, Zb);
      Zc = MFMA16(ah, bl, Zc); Zd = MFMA16(al, bl, Zd);
    }
  };

  const f32x4 zero4 = {0.f, 0.f, 0.f, 0.f};

  // ---------------- recurrence: two autonomous wave programs ----------------
  if (w == 0){
    // wave0: h0(t) = tanh(x@k0 + h(t-1)@rk0 + b0); posts 2t+1
    for (int t = 0; t < T; ++t){
      // emb A-fragments (exchange-independent; fills the flag-arrival window)
      short8 eh[4], el[4];
      int tok = sTok[m][t];
      #pragma unroll
      for (int kk = 0; kk < 4; ++kk){
        #pragma unroll
        for (int j = 0; j < 8; ++j){
          int k = kk*32 + q*8 + j;
          float v = (k < E) ? emb[tok*E + k] : 0.f;
          short hi = f2bf(v);
          short lo = f2bf(v - bf2f(hi));
          eh[kk][j] = hi; el[kk][j] = lo;
        }
      }
      f32x4 za = zero4, zb = zero4, zc = zero4, zd = zero4;
      #pragma unroll
      for (int kk = 0; kk < 4; ++kk){
        za = MFMA16(eh[kk], k0h[kk], za); zb = MFMA16(el[kk], k0h[kk], zb);
        zc = MFMA16(eh[kk], k0l[kk], zc); zd = MFMA16(el[kk], k0l[kk], zd);
      }
      if (t > 0){
        pollF(2*t);                                    // h(t-1) ready
        mm16(((t-1)&1) ? hPkB : hPkA, 0, 1, za, zb, zc, zd);
      }
      f32x4 z = za; z += zb; z += zc; z += zd;
      #pragma unroll
      for (int r = 0; r < 4; ++r){
        float h0v = fast_tanh(z[r] + sB0[m]);
        short hi = f2bf(h0v);
        short lo = f2bf(h0v - bf2f(hi));
        unsigned pk = ((unsigned)(unsigned short)hi << 16) | (unsigned short)lo;
        h0Pk[(cl*16 + q*4 + r)*U + mem*16 + m] = pk;   // plain store (data path)
      }
      postF(2*t + 1);
    }
  } else {
    // wave1: h(t) = tanh(h0(t)@k1 + h(t-1)@rk1 + b1); posts 2t+2
    for (int t = 0; t < T; ++t){
      f32x4 z1a = zero4, z1b = zero4, z1c = zero4, z1d = zero4;
      f32x4 za  = zero4, zb  = zero4, zc  = zero4, zd  = zero4;
      if (t > 0){
        pollF(2*t);                                    // h(t-1) ready
        mm16(((t-1)&1) ? hPkB : hPkA, 2, 3, z1a, z1b, z1c, z1d);
      }
      pollF(2*t + 1);                                  // h0(t) ready
      mm16(h0Pk, 4, 5, za, zb, zc, zd);
      f32x4 z = za; z += zb; z += zc; z += zd;
      z += z1a; z += z1b; z += z1c; z += z1d;
      unsigned* hDst = (t&1) ? hPkB : hPkA;
      #pragma unroll
      for (int r = 0; r < 4; ++r){
        float h1v = fast_tanh(z[r] + sB1[m]);
        short hi = f2bf(h1v);
        short lo = f2bf(h1v - bf2f(hi));
        unsigned pk = ((unsigned)(unsigned short)hi << 16) | (unsigned short)lo;
        hDst[(cl*16 + q*4 + r)*U + mem*16 + m] = pk;   // plain store (data path)
      }
      postF(2*t + 2);
    }
  }

  // ---------------- epilogue: logits = h@wd + bd ; sigmoid ----------------
  // h(T-1) lives in parity (T-1)&1 = 1 -> hPkB. Each wave handles its 8 rows.
  if (mem == 0){
    pollF(2*T);
    int row = w*8 + (lane >> 3), seg = lane & 7;
    const unsigned* hp = hPkB + (cl*16 + row)*U + seg*64;
    float acc = 0.f;
    #pragma unroll
    for (int b = 0; b < 4; ++b){
      uint4 r0, r1, r2, r3;
      const unsigned* pb = hp + b*16;
      GLOAD4(r0, pb); GLOAD4(r1, pb + 4); GLOAD4(r2, pb + 8); GLOAD4(r3, pb + 12);
      asm volatile("s_waitcnt vmcnt(0)" ::: "memory");
      const float* wb = wd + seg*64 + b*16;
      uint4 rs[4] = { r0, r1, r2, r3 };
      #pragma unroll
      for (int v4 = 0; v4 < 4; ++v4){
        acc += (bf2f((short)(rs[v4].x >> 16)) + bf2f((short)(rs[v4].x & 0xffff))) * wb[v4*4 + 0];
        acc += (bf2f((short)(rs[v4].y >> 16)) + bf2f((short)(rs[v4].y & 0xffff))) * wb[v4*4 + 1];
        acc += (bf2f((short)(rs[v4].z >> 16)) + bf2f((short)(rs[v4].z & 0xffff))) * wb[v4*4 + 2];
        acc += (bf2f((short)(rs[v4].w >> 16)) + bf2f((short)(rs[v4].w & 0xffff))) * wb[v4*4 + 3];
      }
    }
    acc += __shfl_xor(acc, 1);
    acc += __shfl_xor(acc, 2);
    acc += __shfl_xor(acc, 4);
    if (seg == 0) out[cl*16 + row] = 1.f / (1.f + __expf(-(acc + bd[0])));
  }

  // replay hygiene (one-time cost)
  __threadfence();
}

extern "C" void kernel_launch(void* const* d_in, const int* in_sizes, int n_in,
                              void* d_out, int out_size, void* d_ws, size_t ws_size,
                              hipStream_t stream) {
  const int*   tokens = (const int*)  d_in[0];
  const float* emb    = (const float*)d_in[1];
  const float* k0     = (const float*)d_in[2];
  const float* rk0    = (const float*)d_in[3];
  const float* b0     = (const float*)d_in[4];
  const float* k1     = (const float*)d_in[5];
  const float* rk1    = (const float*)d_in[6];
  const float* b1     = (const float*)d_in[7];
  const float* wd     = (const float*)d_in[8];
  const float* bd     = (const float*)d_in[9];

  // Zero registration counters + flag region (0xAA poison breaks monotonic
  // arith). regCnt@512, flags@4096..36864; data @40960: h0Pk 256KB + hPk
  // 2x256KB (parity double-buffer) = 768KB, all fully written before read.
  hipMemsetAsync(d_ws, 0, 40960, stream);

  hipLaunchKernelGGL(rnn_kernel, dim3(256), dim3(128), 0, stream,
                     tokens, emb, k0, rk0, b0, k1, rk1, b1, wd, bd,
                     (float*)d_out, (char*)d_ws);
}

// Round 11
// 616.098 us; speedup vs baseline: 1.0679x; 1.0679x over previous
//
#include <hip/hip_runtime.h>

// MyRNN: B=128, T=80, E=100, V=10000, U=512
// 8 clusters x 32 member-blocks, formed DYNAMICALLY by physical XCD
// (s_getreg HW_REG_XCC_ID + atomic slot grab): with 156KB LDS -> 1 block/CU,
// grid 256 fills all CUs -> each XCD hosts exactly 32 blocks -> a cluster's
// members share one L2 BY CONSTRUCTION. Cluster c owns batch rows
// [16c,16c+16); member m owns cols [16m,16m+16) of rk0/rk1/k1 (LDS, hi/lo).
// Chain model: dur = 80 x (2L + w). Protocol history:
// R7 745 -> R9 588 (parallel MALL flags) -> R12 572 (BEST: sE overlap,
// w0-poll, 128B stride). R13 652 / R14 826 / R15 786 / R16 572(neutral) /
// R17 598: w-side and alternative-protocol attempts all bracket
// L ~ 2.3-2.65us as MALL propagation+detection physics.
// HW facts: fire-and-forget plain stores to a flag line linger pre-L2
// (R8 hang, R10 always-timeout); global atomics execute memory-side and
// write HBM (R11); BUT plain data stores + s_waitcnt vmcnt(0) ARE reliably
// visible in L2 to other CUs' sc0 loads (every gather since R7).
// R18: the ONE untested combination -- L2 flag committed by ITS OWN drain:
//   post: data drain -> lane0 plain-stores round id to L2 flag (128B stride)
//         AND to the R9 MALL flag -> drain (ack => both committed).
//   poll (wave0 only, R12 structure): hybrid -- 6 fast sc0 L2-flag iters
//         (~150ns each), then one authoritative MALL check, repeat. No
//         timeout cliff: MALL path guarantees termination; if L2 flags are
//         prompt the MALL check is rarely reached.
//   hygiene (R10-validated): prologue zero-store of own L2 flag + drain +
//         MALL rendezvous on a separate memset-zeroed word before any poll;
//         end __threadfence. Monotonic flags 2t+1/2t+2, no resets.

typedef __attribute__((ext_vector_type(8))) short short8;
typedef __attribute__((ext_vector_type(4))) float f32x4;

#define MFMA16(a,b,c) __builtin_amdgcn_mfma_f32_16x16x32_bf16(a,b,c,0,0,0)
#define LOAD_RLX(p)    __hip_atomic_load((p), __ATOMIC_RELAXED, __HIP_MEMORY_SCOPE_AGENT)
#define STORE_RLX(p,v) __hip_atomic_store((p), (v), __ATOMIC_RELAXED, __HIP_MEMORY_SCOPE_AGENT)
#define ADD_RLX(p,v)   __hip_atomic_fetch_add((p), (v), __ATOMIC_RELAXED, __HIP_MEMORY_SCOPE_AGENT)

__device__ __forceinline__ short f2bf(float v){
  unsigned u = __float_as_uint(v);
  u = (u + 0x7fffu + ((u >> 16) & 1u)) >> 16;   // RNE to bf16
  return (short)u;
}
__device__ __forceinline__ float bf2f(short s){
  return __uint_as_float(((unsigned)(unsigned short)s) << 16);
}
__device__ __forceinline__ float fast_tanh(float x){
  x = fminf(15.f, fmaxf(-15.f, x));
  float e = __expf(2.f * x);
  return (e - 1.f) * __builtin_amdgcn_rcpf(e + 1.f);
}

__launch_bounds__(128, 1)
__global__ void rnn_kernel(const int* __restrict__ tokens,
                           const float* __restrict__ emb,
                           const float* __restrict__ k0,
                           const float* __restrict__ rk0,
                           const float* __restrict__ b0,
                           const float* __restrict__ k1,
                           const float* __restrict__ rk1,
                           const float* __restrict__ b1,
                           const float* __restrict__ wd,
                           const float* __restrict__ bd,
                           float* __restrict__ out,
                           char* __restrict__ ws)
{
  constexpr int T = 80, E = 100, U = 512;
  const int tid  = threadIdx.x;
  const int w    = tid >> 6;          // wave id (0/1)
  const int lane = tid & 63;
  const int m    = lane & 15;         // row (A) / col (B,C)
  const int q    = lane >> 4;         // quad 0..3

  __shared__ __align__(16) short sW[6][16][520];   // rk0 hi/lo, rk1 hi/lo, k1 hi/lo : [col][k]
  __shared__ __align__(16) short sH[2][16][520];   // h / h0 staging hi,lo : [row][k]
  __shared__ __align__(16) short sE[2][16][136];   // emb rows hi,lo (K padded to 128 w/ zeros)
  __shared__ __align__(16) short sK0[2][16][136];  // k0 slice hi,lo : [col][k] (padded)
  __shared__ int   sTok[16][80];
  __shared__ float sB0[16], sB1[16];
  __shared__ float sRed[16][8];
  __shared__ int   sReg[2];

  // ws layout: regCnt@512; flagsM(MALL)@4096 (256 x 128B); flagsR(MALL
  // rendezvous)@36864 (256 x 8B); flagsL(L2)@40960 (256 x 128B); data@73728.
  int*      regCnt = (int*)(ws + 512);
  int*      flagsM = (int*)(ws + 4096);
  int*      flagsR = (int*)(ws + 36864);
  int*      flagsL = (int*)(ws + 40960);
  unsigned* hPk    = (unsigned*)(ws + 73728);      // h1 packed (hi<<16|lo), [128][512]
  unsigned* h0Pk   = hPk + 128*U;                  // h0 packed

  // -------- dynamic cluster formation: cluster id = physical XCD --------
  int xcc;
  asm volatile("s_getreg_b32 %0, hwreg(HW_REG_XCC_ID)" : "=s"(xcc));
  if (tid == 0){
    int slot = ADD_RLX(regCnt + (xcc & 7)*16, 1);  // 0..31 within this XCD
    sReg[0] = xcc & 7;
    sReg[1] = slot;
  }
  __syncthreads();
  const int cl  = sReg[0];
  const int mem = sReg[1];
  int* const myFlagM   = flagsM + (cl*32 + mem)*32;
  int* const pollAddrM = flagsM + (cl*32 + (lane & 31))*32;
  int* const myFlagR   = flagsR + (cl*32 + mem)*2;
  int* const pollAddrR = flagsR + (cl*32 + (lane & 31))*2;
  int* const myFlagL   = flagsL + (cl*32 + mem)*32;
  int* const pollAddrL = flagsL + (cl*32 + (lane & 31))*32;

  // ---------------- prologue: stationary weights -> LDS ----------------
  const float* mats[3] = { rk0, rk1, k1 };
  for (int mi = 0; mi < 3; ++mi){
    const float* G = mats[mi];
    for (int i = tid; i < 16*U; i += 128){
      int k = i >> 4, c = i & 15;
      float v  = G[k*U + mem*16 + c];
      short hi = f2bf(v);
      short lo = f2bf(v - bf2f(hi));
      sW[2*mi+0][c][k] = hi;
      sW[2*mi+1][c][k] = lo;
    }
  }
  for (int i = tid; i < 2*16*136; i += 128){ ((short*)sE)[i] = 0; ((short*)sK0)[i] = 0; }
  __syncthreads();
  for (int i = tid; i < 16*E; i += 128){
    int e = i >> 4, c = i & 15;
    float v  = k0[e*U + mem*16 + c];
    short hi = f2bf(v);
    short lo = f2bf(v - bf2f(hi));
    sK0[0][c][e] = hi; sK0[1][c][e] = lo;
  }
  for (int i = tid; i < 16*T; i += 128){
    int r = i / T, t = i - r*T;
    sTok[r][t] = tokens[(cl*16 + r)*T + t];
  }
  if (tid < 16){ sB0[tid] = b0[mem*16 + tid]; sB1[tid] = b1[mem*16 + tid]; }
  __syncthreads();

  // -------- L2-flag replay hygiene (R10-validated): zero own flag with a
  // DRAINED write-through store (overwrites any stale dirty line from the
  // previous graph replay in this XCD's L2), then MALL rendezvous on a
  // separate memset-zeroed word before anyone polls an L2 flag.
  if (tid == 0){
    int z = 0;
    asm volatile("global_store_dword %0, %1, off" :: "v"(myFlagL), "v"(z) : "memory");
    asm volatile("s_waitcnt vmcnt(0)" ::: "memory");
    STORE_RLX(myFlagR, 1);
  }
  if (w == 0){ while (__any(LOAD_RLX(pollAddrR) < 1)) {} }
  __syncthreads();

  // post: drain data stores, then lane0 stores the round id to the L2 flag
  // (write-through) AND the MALL flag, then drains again -- the second ack
  // forces the L2 flag line out of the store/WC buffer (the mechanism R10
  // was missing). Cost ~0.2us on the producer, off the consumer path.
  auto post = [&](int val){
    asm volatile("s_waitcnt vmcnt(0)" ::: "memory");
    if (lane == 0){
      asm volatile("global_store_dword %0, %1, off" :: "v"(myFlagL), "v"(val) : "memory");
      STORE_RLX(myFlagM, val);
    }
    asm volatile("s_waitcnt vmcnt(0)" ::: "memory");
  };
  // hybrid wave-parallel poll (WAVE0 ONLY; barrier releases w1): 6 fast L2
  // iterations (sc0, ~150ns each), then one authoritative MALL check; loop.
  // Termination guaranteed by the MALL path regardless of L2-flag behavior.
  auto pollFlags = [&](int target){
    for (;;){
      #pragma unroll 1
      for (int it = 0; it < 6; ++it){
        int v;
        asm volatile("global_load_dword %0, %1, off sc0\n\t"
                     "s_waitcnt vmcnt(0)"
                     : "=v"(v) : "v"(pollAddrL) : "memory");
        if (!__any(v < target)) return;
      }
      if (!__any(LOAD_RLX(pollAddrM) < target)) return;
    }
  };
  // gather: 16x dwordx4 sc0, then unpack into sH hi/lo.
  auto gather = [&](const unsigned* srcPk){
    const uint4* s = (const uint4*)(srcPk + cl*16*U);   // 2048 uint4 = 32 KB
    uint4 r[16];
    #pragma unroll
    for (int j = 0; j < 16; ++j)
      asm volatile("global_load_dwordx4 %0, %1, off sc0"
                   : "=v"(r[j]) : "v"(&s[j*128 + tid]));
    asm volatile("s_waitcnt vmcnt(0)" ::: "memory");
    #pragma unroll
    for (int j = 0; j < 16; ++j){
      int i = j*128 + tid, row = i >> 7, c = (i & 127) * 4;
      unsigned h0 = (r[j].x >> 16)     | (r[j].y & 0xffff0000u);
      unsigned h1 = (r[j].z >> 16)     | (r[j].w & 0xffff0000u);
      unsigned l0 = (r[j].x & 0xffffu) | (r[j].y << 16);
      unsigned l1 = (r[j].z & 0xffffu) | (r[j].w << 16);
      uint2 hh; hh.x = h0; hh.y = h1;
      uint2 ll; ll.x = l0; ll.y = l1;
      *(uint2*)&sH[0][row][c] = hh;
      *(uint2*)&sH[1][row][c] = ll;
    }
  };

  const f32x4 zero4 = {0.f, 0.f, 0.f, 0.f};

  // ---------------- recurrence ----------------
  for (int t = 0; t < T; ++t){
    // wave1 stages sE[t] OFF the critical path while wave0 polls.
    if (w == 1){
      float ev[25];
      #pragma unroll
      for (int p = 0; p < 25; ++p){
        int i = lane + p*64;                 // 25*64 = 1600 = 16*E exactly
        ev[p] = emb[sTok[i/E][t]*E + (i % E)];
      }
      #pragma unroll
      for (int p = 0; p < 25; ++p){
        int i = lane + p*64;
        int row = i / E, e = i % E;
        short hi = f2bf(ev[p]);
        short lo = f2bf(ev[p] - bf2f(hi));
        sE[0][row][e] = hi; sE[1][row][e] = lo;
      }
    } else {
      if (t > 0) pollFlags(2*t);             // all round-B(t-1) posts
    }
    __syncthreads();
    if (t > 0) gather(hPk);
    __syncthreads();

    // ---- round A: wave0: h0 = tanh(x@k0 + h@rk0 + b0); wave1: h@rk1 partial
    f32x4 z1a = zero4, z1b = zero4, z1c = zero4, z1d = zero4;
    if (w == 0){
      f32x4 za = zero4, zb = zero4, zc = zero4, zd = zero4;
      #pragma unroll
      for (int kk = 0; kk < 4; ++kk){
        short8 ah = *(const short8*)&sE[0][m][kk*32 + q*8];
        short8 al = *(const short8*)&sE[1][m][kk*32 + q*8];
        short8 bh = *(const short8*)&sK0[0][m][kk*32 + q*8];
        short8 bl = *(const short8*)&sK0[1][m][kk*32 + q*8];
        za = MFMA16(ah, bh, za); zb = MFMA16(al, bh, zb);
        zc = MFMA16(ah, bl, zc); zd = MFMA16(al, bl, zd);
      }
      if (t > 0){
        #pragma unroll
        for (int kk = 0; kk < 16; ++kk){
          short8 ah = *(const short8*)&sH[0][m][kk*32 + q*8];
          short8 al = *(const short8*)&sH[1][m][kk*32 + q*8];
          short8 bh = *(const short8*)&sW[0][m][kk*32 + q*8];
          short8 bl = *(const short8*)&sW[1][m][kk*32 + q*8];
          za = MFMA16(ah, bh, za); zb = MFMA16(al, bh, zb);
          zc = MFMA16(ah, bl, zc); zd = MFMA16(al, bl, zd);
        }
      }
      f32x4 z = za; z += zb; z += zc; z += zd;
      #pragma unroll
      for (int r = 0; r < 4; ++r){
        float h0v = fast_tanh(z[r] + sB0[m]);
        short hi = f2bf(h0v);
        short lo = f2bf(h0v - bf2f(hi));
        int gr = cl*16 + q*4 + r, gc = mem*16 + m;
        unsigned pk = ((unsigned)(unsigned short)hi << 16) | (unsigned short)lo;
        h0Pk[gr*U + gc] = pk;              // plain store (data path)
      }
      post(2*t + 1);                       // h0 ready (this member)
    } else {
      if (t > 0){
        #pragma unroll
        for (int kk = 0; kk < 16; ++kk){
          short8 ah = *(const short8*)&sH[0][m][kk*32 + q*8];
          short8 al = *(const short8*)&sH[1][m][kk*32 + q*8];
          short8 bh = *(const short8*)&sW[2][m][kk*32 + q*8];
          short8 bl = *(const short8*)&sW[3][m][kk*32 + q*8];
          z1a = MFMA16(ah, bh, z1a); z1b = MFMA16(al, bh, z1b);
          z1c = MFMA16(ah, bl, z1c); z1d = MFMA16(al, bl, z1d);
        }
      }
    }

    // ---- round B: h1 = tanh(h0@k1 + h@rk1 + b1)
    if (w == 0) pollFlags(2*t + 1);        // all round-A posts (w1 finishing z1)
    __syncthreads();                       // releases w1; round-A sH reads retired
    gather(h0Pk);
    __syncthreads();
    if (w == 1){
      f32x4 za = zero4, zb = zero4, zc = zero4, zd = zero4;
      #pragma unroll
      for (int kk = 0; kk < 16; ++kk){
        short8 ah = *(const short8*)&sH[0][m][kk*32 + q*8];
        short8 al = *(const short8*)&sH[1][m][kk*32 + q*8];
        short8 bh = *(const short8*)&sW[4][m][kk*32 + q*8];
        short8 bl = *(const short8*)&sW[5][m][kk*32 + q*8];
        za = MFMA16(ah, bh, za); zb = MFMA16(al, bh, zb);
        zc = MFMA16(ah, bl, zc); zd = MFMA16(al, bl, zd);
      }
      f32x4 z = za; z += zb; z += zc; z += zd;
      z += z1a; z += z1b; z += z1c; z += z1d;
      #pragma unroll
      for (int r = 0; r < 4; ++r){
        float h1v = fast_tanh(z[r] + sB1[m]);
        short hi = f2bf(h1v);
        short lo = f2bf(h1v - bf2f(hi));
        int gr = cl*16 + q*4 + r, gc = mem*16 + m;
        unsigned pk = ((unsigned)(unsigned short)hi << 16) | (unsigned short)lo;
        hPk[gr*U + gc] = pk;               // plain store (data path)
      }
      post(2*t + 2);                       // h1 = h(t) ready (this member)
    }
    // no trailing barrier: loop-top poll+barrier aligns waves
  }

  // ---------------- epilogue: logits = h@wd + bd ; sigmoid ----------------
  if (mem == 0){
    if (w == 0) pollFlags(2*T);
    __syncthreads();
    gather(hPk);
    __syncthreads();
    {
      int row = tid >> 3, seg = tid & 7;
      float acc = 0.f;
      for (int u = seg*64; u < seg*64 + 64; ++u){
        float hv = bf2f(sH[0][row][u]) + bf2f(sH[1][row][u]);
        acc += hv * wd[u];
      }
      sRed[row][seg] = acc;
    }
    __syncthreads();
    if (tid < 16){
      float s = bd[0];
      #pragma unroll
      for (int j = 0; j < 8; ++j) s += sRed[tid][j];
      out[cl*16 + tid] = 1.f / (1.f + __expf(-s));
    }
  }

  // replay hygiene: flush this XCD's dirty L2 exchange+flag lines (one-time)
  __threadfence();
}

extern "C" void kernel_launch(void* const* d_in, const int* in_sizes, int n_in,
                              void* d_out, int out_size, void* d_ws, size_t ws_size,
                              hipStream_t stream) {
  const int*   tokens = (const int*)  d_in[0];
  const float* emb    = (const float*)d_in[1];
  const float* k0     = (const float*)d_in[2];
  const float* rk0    = (const float*)d_in[3];
  const float* b0     = (const float*)d_in[4];
  const float* k1     = (const float*)d_in[5];
  const float* rk1    = (const float*)d_in[6];
  const float* b1     = (const float*)d_in[7];
  const float* wd     = (const float*)d_in[8];
  const float* bd     = (const float*)d_in[9];

  // Zero registration counters + all flag regions (0xAA poison breaks
  // monotonic arith). regCnt@512, flagsM@4096..36864, flagsR@36864..38912,
  // flagsL@40960..73728; exchange data starts at 73728 (fully rewritten at
  // t=0 before first gather -- no memset needed there).
  hipMemsetAsync(d_ws, 0, 73728, stream);

  hipLaunchKernelGGL(rnn_kernel, dim3(256), dim3(128), 0, stream,
                     tokens, emb, k0, rk0, b0, k1, rk1, b1, wd, bd,
                     (float*)d_out, (char*)d_ws);
}